// Round 1
// baseline (348.428 us; speedup 1.0000x reference)
//
#include <hip/hip_runtime.h>

// CRF forward partition (log-partition-function sum), MI355X.
// B=1024 batches, L=512 timesteps, T=52 tags.
//
// p-space recurrence: p_new[j] = exp(f[t,j]) * sum_i E[i][j]*p[i],
// E = exp(transitions) precomputed per-lane (constant across t,b).
// One wave per batch; lane j owns tag j; p kept wave-uniform in SGPRs
// via v_readlane so the matvec is v_fmac(vdst, sgpr, vgpr) with no LDS.

#define TT 52   // TAG_SIZE
#define LL 512  // sequence length
#define PF 4    // feats/mask prefetch depth (steps)

__device__ __forceinline__ float rl(float x, int lane) {
    return __int_as_float(__builtin_amdgcn_readlane(__float_as_int(x), lane));
}

__global__ void __launch_bounds__(64) crf_fwd(
    const float* __restrict__ feats,   // (B, L, T)
    const int*   __restrict__ mask,    // (B, L)
    const float* __restrict__ trans,   // (T, T)
    float*       __restrict__ out)     // scalar accumulator (pre-zeroed)
{
    const int b = blockIdx.x;
    const int j = threadIdx.x;          // lane = destination tag
    const bool act = (j < TT);

    const float* fb = feats + (size_t)b * LL * TT;
    const int*   mb = mask  + (size_t)b * LL;

    // Per-lane transition column: E[i] = exp(trans[i][j]).
    // -1000 entries (START col / END row) become exact 0.
    float E[TT];
#pragma unroll
    for (int i = 0; i < TT; ++i)
        E[i] = act ? __expf(trans[i * TT + j]) : 0.0f;

    // t=0 init: part0[j] = feats[b,0,j] + trans[START][j]; normalize by lane 0.
    float part0 = act ? (fb[j] + trans[(TT - 2) * TT + j]) : -1.0e30f;
    float shift = rl(part0, 0);
    float pv = act ? __expf(part0 - shift) : 0.0f;   // lane j holds p[j]

    // Wave-uniform copy of p (SGPRs via readlane).
    float ps[TT];
#pragma unroll
    for (int i = 0; i < TT; ++i) ps[i] = rl(pv, i);

    // Prefetch ring: feats (per-lane) + mask (wave-uniform scalar).
    float fpre[PF];
    int   mc[PF];
#pragma unroll
    for (int u = 0; u < PF; ++u) {
        int t = 1 + u;
        fpre[u] = (act && t < LL) ? fb[t * TT + j] : 0.0f;
        mc[u]   = (t < LL) ? mb[t] : 0;
    }

    for (int t0 = 1; t0 < LL; t0 += PF) {
        // issue next group's loads first (~4 steps => ~900+ cyc of slack)
        float fnx[PF];
        int   mn[PF];
#pragma unroll
        for (int u = 0; u < PF; ++u) {
            int tn = t0 + PF + u;
            fnx[u] = (act && tn < LL) ? fb[tn * TT + j] : 0.0f;
            mn[u]  = (tn < LL) ? mb[tn] : 0;
        }

#pragma unroll
        for (int u = 0; u < PF; ++u) {
            int tt = t0 + u;
            if (tt >= LL) continue;           // uniform; last group only
            float ef = __expf(fpre[u]);
            if (mc[u] > 0) {
                // s_j = sum_i E[i][j] * p[i]  (4 independent FMA chains)
                float a0 = 0.f, a1 = 0.f, a2 = 0.f, a3 = 0.f;
#pragma unroll
                for (int i = 0; i < TT; i += 4) {
                    a0 = fmaf(ps[i + 0], E[i + 0], a0);
                    a1 = fmaf(ps[i + 1], E[i + 1], a1);
                    a2 = fmaf(ps[i + 2], E[i + 2], a2);
                    a3 = fmaf(ps[i + 3], E[i + 3], a3);
                }
                float s  = (a0 + a1) + (a2 + a3);
                float pn = s * ef;
                // normalize by lane 0's value (always > 0); track log-shift
                float c = rl(pn, 0);
                shift += __logf(c);
                float inv = __builtin_amdgcn_rcpf(c);
                pv = pn * inv;
#pragma unroll
                for (int i = 0; i < TT; ++i) ps[i] = rl(pv, i);
            }
        }
#pragma unroll
        for (int u = 0; u < PF; ++u) { fpre[u] = fnx[u]; mc[u] = mn[u]; }
    }

    // Final: LSE_i(trans[i][END] + part[i]) = log(sum_i exp(trans[i][END])*p[i]) + shift
    float val = act ? (__expf(trans[j * TT + (TT - 1)]) * pv) : 0.0f;
#pragma unroll
    for (int o = 32; o >= 1; o >>= 1)
        val += __shfl_xor(val, o, 64);
    if (j == 0) atomicAdd(out, __logf(val) + shift);
}

extern "C" void kernel_launch(void* const* d_in, const int* in_sizes, int n_in,
                              void* d_out, int out_size, void* d_ws, size_t ws_size,
                              hipStream_t stream) {
    const float* feats = (const float*)d_in[0];
    const int*   mask  = (const int*)d_in[1];
    const float* trans = (const float*)d_in[2];
    float* out = (float*)d_out;

    const int B = in_sizes[1] / LL;   // mask is (B, L)

    hipMemsetAsync(d_out, 0, sizeof(float), stream);
    crf_fwd<<<B, 64, 0, stream>>>(feats, mask, trans, out);
}

// Round 2
// 257.428 us; speedup vs baseline: 1.3535x; 1.3535x over previous
//
#include <hip/hip_runtime.h>

// CRF forward partition, MI355X. B=1024, L=512, T=52.
//
// p-space recurrence: p_new[j] = exp(f[t,j]) * sum_i E[i][j]*p[i],
// E = exp(transitions), constant. One wave per batch; lane j owns tag j;
// p broadcast wave-uniform via v_readlane so the matvec is
// v_fmac(v, s, v). R2 changes vs R1:
//  - __launch_bounds__(64,1): full VGPR budget (R1's VGPR=36 => E spilled)
//  - branchless mask select + clamped prefetch (no uniform branches in body)
//  - normalize only once per 4-step group (log/rcp off the critical path)

#define TT 52   // TAG_SIZE
#define LL 512  // sequence length
#define NS 4    // steps per group; normalize once per group

__device__ __forceinline__ float rl(float x, int lane) {
    return __int_as_float(__builtin_amdgcn_readlane(__float_as_int(x), lane));
}

__global__ void __launch_bounds__(64, 1) crf_fwd(
    const float* __restrict__ feats,   // (B, L, T)
    const int*   __restrict__ mask,    // (B, L)
    const float* __restrict__ trans,   // (T, T)
    float*       __restrict__ out)     // scalar accumulator (pre-zeroed)
{
    const int b = blockIdx.x;
    const int j = threadIdx.x;          // lane = destination tag
    const bool act = (j < TT);
    const int jc = act ? j : 0;         // clamped lane index for safe loads

    const float* fb = feats + (size_t)b * LL * TT;
    const int*   mb = mask  + (size_t)b * LL;

    // Per-lane transition column: E[i] = exp(trans[i][j]).
    // -1000 entries (START col / END row) become exact 0.
    float E[TT];
#pragma unroll
    for (int i = 0; i < TT; ++i) {
        float e = __expf(trans[i * TT + jc]);
        E[i] = act ? e : 0.0f;
    }

    // t=0 init: part0[j] = feats[b,0,j] + trans[START][j]; normalize by lane 0.
    float part0 = act ? (fb[j] + trans[(TT - 2) * TT + j]) : -1.0e30f;
    float shift = rl(part0, 0);
    float pv = act ? __expf(part0 - shift) : 0.0f;   // lane j holds p[j]

    // Wave-uniform copy of p (targets SGPRs via readlane).
    float ps[TT];
#pragma unroll
    for (int i = 0; i < TT; ++i) ps[i] = rl(pv, i);

    // Prefetch ring (clamped indices => no guard branches, always in-bounds).
    float fpre[NS];
    int   mc[NS];
#pragma unroll
    for (int u = 0; u < NS; ++u) {
        int t = 1 + u;                  // all < LL
        fpre[u] = fb[t * TT + jc];
        mc[u]   = mb[t];
    }

    // Main loop: 127 branch-free groups covering t = 1 .. 508.
    for (int t0 = 1; t0 < LL - NS + 1; t0 += NS) {
        // issue next group's loads first (~4 steps of latency slack)
        float fnx[NS];
        int   mn[NS];
#pragma unroll
        for (int u = 0; u < NS; ++u) {
            int tn = t0 + NS + u;
            int tcl = tn < LL ? tn : (LL - 1);   // clamp (tail overrun harmless)
            fnx[u] = fb[tcl * TT + jc];
            mn[u]  = mb[tcl];
        }

#pragma unroll
        for (int u = 0; u < NS; ++u) {
            float ef = __expf(fpre[u]);
            // s_j = sum_i E[i][j] * p[i]  (4 independent FMA chains)
            float a0 = 0.f, a1 = 0.f, a2 = 0.f, a3 = 0.f;
#pragma unroll
            for (int i = 0; i < TT; i += 4) {
                a0 = fmaf(ps[i + 0], E[i + 0], a0);
                a1 = fmaf(ps[i + 1], E[i + 1], a1);
                a2 = fmaf(ps[i + 2], E[i + 2], a2);
                a3 = fmaf(ps[i + 3], E[i + 3], a3);
            }
            float pn = ((a0 + a1) + (a2 + a3)) * ef;
            pv = (mc[u] > 0) ? pn : pv;          // branchless mask select
            if (u == NS - 1) {
                // normalize once per group by lane 0 (>0 always); track shift
                float c = rl(pv, 0);
                shift += __logf(c);
                pv *= __builtin_amdgcn_rcpf(c);
            }
#pragma unroll
            for (int i = 0; i < TT; ++i) ps[i] = rl(pv, i);
        }
#pragma unroll
        for (int u = 0; u < NS; ++u) { fpre[u] = fnx[u]; mc[u] = mn[u]; }
    }

    // Tail: t = 509, 510, 511 (3 steps, data already in fpre[0..2]).
#pragma unroll
    for (int u = 0; u < 3; ++u) {
        float ef = __expf(fpre[u]);
        float a0 = 0.f, a1 = 0.f, a2 = 0.f, a3 = 0.f;
#pragma unroll
        for (int i = 0; i < TT; i += 4) {
            a0 = fmaf(ps[i + 0], E[i + 0], a0);
            a1 = fmaf(ps[i + 1], E[i + 1], a1);
            a2 = fmaf(ps[i + 2], E[i + 2], a2);
            a3 = fmaf(ps[i + 3], E[i + 3], a3);
        }
        float pn = ((a0 + a1) + (a2 + a3)) * ef;
        pv = (mc[u] > 0) ? pn : pv;
#pragma unroll
        for (int i = 0; i < TT; ++i) ps[i] = rl(pv, i);
    }

    // Final: log(sum_i exp(trans[i][END]) * p[i]) + shift
    float eend = __expf(trans[jc * TT + (TT - 1)]);
    float val = act ? (eend * pv) : 0.0f;
#pragma unroll
    for (int o = 32; o >= 1; o >>= 1)
        val += __shfl_xor(val, o, 64);
    if (j == 0) atomicAdd(out, __logf(val) + shift);
}

extern "C" void kernel_launch(void* const* d_in, const int* in_sizes, int n_in,
                              void* d_out, int out_size, void* d_ws, size_t ws_size,
                              hipStream_t stream) {
    const float* feats = (const float*)d_in[0];
    const int*   mask  = (const int*)d_in[1];
    const float* trans = (const float*)d_in[2];
    float* out = (float*)d_out;

    const int B = in_sizes[1] / LL;   // mask is (B, L)

    hipMemsetAsync(d_out, 0, sizeof(float), stream);
    crf_fwd<<<B, 64, 0, stream>>>(feats, mask, trans, out);
}

// Round 3
// 257.138 us; speedup vs baseline: 1.3550x; 1.0011x over previous
//
#include <hip/hip_runtime.h>

// CRF forward partition, MI355X. B=1024, L=512, T=52.
//
// p-space recurrence: p_new[j] = exp(f[t,j]) * sum_i E[i][j]*p[i],
// E = exp(transitions), constant. One wave per batch; lane j owns tag j;
// p broadcast wave-uniform via v_readlane (ps -> SGPRs, confirmed R2:
// SGPR_Count=96) so the matvec is v_fmac(v, s, v).
//
// R3 vs R2: force E[52] into architectural VGPRs. R2 showed VGPR=36 with
// no scratch traffic => allocator parked E in AGPRs, paying ~52
// v_accvgpr_read/step (+deps). Fix: amdgpu_waves_per_eu(1) + inline-asm
// "+v" pinning of E at the top of every outer iteration.

#define TT 52   // TAG_SIZE
#define LL 512  // sequence length
#define NS 4    // steps per group; normalize once per group

__device__ __forceinline__ float rl(float x, int lane) {
    return __int_as_float(__builtin_amdgcn_readlane(__float_as_int(x), lane));
}

// Pin 4 consecutive E values to VGPRs (no code emitted).
#define PIN4(k) asm("" : "+v"(E[k]), "+v"(E[k+1]), "+v"(E[k+2]), "+v"(E[k+3]))
#define PIN_ALL_E() do { \
    PIN4(0); PIN4(4); PIN4(8); PIN4(12); PIN4(16); PIN4(20); PIN4(24); \
    PIN4(28); PIN4(32); PIN4(36); PIN4(40); PIN4(44); PIN4(48); } while (0)

__global__ void __launch_bounds__(64, 1)
__attribute__((amdgpu_waves_per_eu(1)))
crf_fwd(
    const float* __restrict__ feats,   // (B, L, T)
    const int*   __restrict__ mask,    // (B, L)
    const float* __restrict__ trans,   // (T, T)
    float*       __restrict__ out)     // scalar accumulator (pre-zeroed)
{
    const int b = blockIdx.x;
    const int j = threadIdx.x;          // lane = destination tag
    const bool act = (j < TT);
    const int jc = act ? j : 0;         // clamped lane index for safe loads

    const float* fb = feats + (size_t)b * LL * TT;
    const int*   mb = mask  + (size_t)b * LL;

    // Per-lane transition column: E[i] = exp(trans[i][j]).
    // -1000 entries (START col / END row) become exact 0.
    float E[TT];
#pragma unroll
    for (int i = 0; i < TT; ++i) {
        float e = __expf(trans[i * TT + jc]);
        E[i] = act ? e : 0.0f;
    }

    // t=0 init: part0[j] = feats[b,0,j] + trans[START][j]; normalize by lane 0.
    float part0 = act ? (fb[j] + trans[(TT - 2) * TT + j]) : -1.0e30f;
    float shift = rl(part0, 0);
    float pv = act ? __expf(part0 - shift) : 0.0f;   // lane j holds p[j]

    // Wave-uniform copy of p (targets SGPRs via readlane).
    float ps[TT];
#pragma unroll
    for (int i = 0; i < TT; ++i) ps[i] = rl(pv, i);

    // Prefetch ring (clamped indices => no guard branches, always in-bounds).
    float fpre[NS];
    int   mc[NS];
#pragma unroll
    for (int u = 0; u < NS; ++u) {
        int t = 1 + u;                  // all < LL
        fpre[u] = fb[t * TT + jc];
        mc[u]   = mb[t];
    }

    // Main loop: 127 branch-free groups covering t = 1 .. 508.
    for (int t0 = 1; t0 < LL - NS + 1; t0 += NS) {
        PIN_ALL_E();   // keep E architectural-VGPR-resident in the loop

        // issue next group's loads first (~4 steps of latency slack)
        float fnx[NS];
        int   mn[NS];
#pragma unroll
        for (int u = 0; u < NS; ++u) {
            int tn = t0 + NS + u;
            int tcl = tn < LL ? tn : (LL - 1);   // clamp (tail overrun harmless)
            fnx[u] = fb[tcl * TT + jc];
            mn[u]  = mb[tcl];
        }

#pragma unroll
        for (int u = 0; u < NS; ++u) {
            float ef = __expf(fpre[u]);
            // s_j = sum_i E[i][j] * p[i]  (4 independent FMA chains)
            float a0 = 0.f, a1 = 0.f, a2 = 0.f, a3 = 0.f;
#pragma unroll
            for (int i = 0; i < TT; i += 4) {
                a0 = fmaf(ps[i + 0], E[i + 0], a0);
                a1 = fmaf(ps[i + 1], E[i + 1], a1);
                a2 = fmaf(ps[i + 2], E[i + 2], a2);
                a3 = fmaf(ps[i + 3], E[i + 3], a3);
            }
            float pn = ((a0 + a1) + (a2 + a3)) * ef;
            pv = (mc[u] > 0) ? pn : pv;          // branchless mask select
            if (u == NS - 1) {
                // normalize once per group by lane 0 (>0 always); track shift
                float c = rl(pv, 0);
                shift += __logf(c);
                pv *= __builtin_amdgcn_rcpf(c);
            }
#pragma unroll
            for (int i = 0; i < TT; ++i) ps[i] = rl(pv, i);
        }
#pragma unroll
        for (int u = 0; u < NS; ++u) { fpre[u] = fnx[u]; mc[u] = mn[u]; }
    }

    // Tail: t = 509, 510, 511 (3 steps, data already in fpre[0..2]).
#pragma unroll
    for (int u = 0; u < 3; ++u) {
        float ef = __expf(fpre[u]);
        float a0 = 0.f, a1 = 0.f, a2 = 0.f, a3 = 0.f;
#pragma unroll
        for (int i = 0; i < TT; i += 4) {
            a0 = fmaf(ps[i + 0], E[i + 0], a0);
            a1 = fmaf(ps[i + 1], E[i + 1], a1);
            a2 = fmaf(ps[i + 2], E[i + 2], a2);
            a3 = fmaf(ps[i + 3], E[i + 3], a3);
        }
        float pn = ((a0 + a1) + (a2 + a3)) * ef;
        pv = (mc[u] > 0) ? pn : pv;
#pragma unroll
        for (int i = 0; i < TT; ++i) ps[i] = rl(pv, i);
    }

    // Final: log(sum_i exp(trans[i][END]) * p[i]) + shift
    float eend = __expf(trans[jc * TT + (TT - 1)]);
    float val = act ? (eend * pv) : 0.0f;
#pragma unroll
    for (int o = 32; o >= 1; o >>= 1)
        val += __shfl_xor(val, o, 64);
    if (j == 0) atomicAdd(out, __logf(val) + shift);
}

extern "C" void kernel_launch(void* const* d_in, const int* in_sizes, int n_in,
                              void* d_out, int out_size, void* d_ws, size_t ws_size,
                              hipStream_t stream) {
    const float* feats = (const float*)d_in[0];
    const int*   mask  = (const int*)d_in[1];
    const float* trans = (const float*)d_in[2];
    float* out = (float*)d_out;

    const int B = in_sizes[1] / LL;   // mask is (B, L)

    hipMemsetAsync(d_out, 0, sizeof(float), stream);
    crf_fwd<<<B, 64, 0, stream>>>(feats, mask, trans, out);
}